// Round 14
// baseline (278.409 us; speedup 1.0000x reference)
//
#include <hip/hip_runtime.h>
#include <climits>

// out[i] = cond * prod_{e: idx[e]==i} factor[e];  cond = 1 - clip(t0,0,1)
// log(factor) = logC - u,  u = 0.5*((v-t2)/t1)^2,  logC = log(t0c*INV_SQRT_2PI/t1)
//
// R14: ringless bin. Model from R8-R13: bin is bound by DS lane-ops/event
// (~2.25-3, all scattered). This kernel cuts DS ops to 1 (position atomic);
// records go DIRECTLY to global 4B-scattered into a 256KB per-block region
// that stays L2-resident, so L2 assembles full lines before eviction (the
// R3 failure was a 427MB active window; here it's 64 blocks/XCD x 256KB).
// No rings -> 2KB LDS -> no in-loop barriers, 4 blocks/CU (32 waves).
// Reduce: R9's verbatim (readlane counts, packed int LDS atomics, cap=128).

#define INV_SQRT_2PI 0.39894246f  // 1/sqrt(2*3.14159) (matches reference)
#define SLOT_BITS 14
#define SLOTS (1 << SLOT_BITS)    // 16384 slots per bucket
#define NB_MAX 512                // buckets (fast-path max)
#define NBLK 512                  // binning blocks (block-private regions)
#define BTHREADS 512
#define QSCALE 8192.0f
#define QMASK 0x3FFFFu            // 18-bit q

__device__ __forceinline__ long long region_idx(int blk, int b, int nbuckets,
                                                int swzmask) {
    int bb = swzmask ? ((b + blk) & swzmask) : b;
    return (long long)blk * nbuckets + bb;
}

__device__ __forceinline__ void ovf_push(uint2* ovf, int* ovf_cnt, int ovcap,
                                         unsigned gslot, unsigned q) {
    int op = atomicAdd(ovf_cnt, 1);
    if (op < ovcap) ovf[op] = make_uint2(gslot, q);
}

__global__ __launch_bounds__(BTHREADS) void bin_kernel(
        const int* __restrict__ idx, const float* __restrict__ vals,
        const float* __restrict__ thetas,
        unsigned* __restrict__ pairs,  // [NBLK][nb][cap] (swizzled regions)
        int* __restrict__ fill,        // [NBLK][nb] valid counts (swizzled)
        uint2* __restrict__ ovf, int* __restrict__ ovf_cnt, int ovcap,
        int n, int nbuckets, int cap_shift, int swzmask, int epb) {
    __shared__ int scnt[NB_MAX];   // 2 KB: per-bucket position counters

    const int tid = threadIdx.x;
    const int blk = blockIdx.x;
    const int cap = 1 << cap_shift;
    long long start = (long long)blk * epb;
    long long end = start + epb;
    if (end > n) end = n;

    for (int b = tid; b < nbuckets; b += BTHREADS) scnt[b] = 0;
    __syncthreads();

    const float t1 = thetas[1], t2 = thetas[2];
    const float t0c = fminf(fmaxf(thetas[0], 0.0f), 1.0f);
    const float inv_t1 = 1.0f / t1;

    // flat loop, 4 events/thread/iter, no barriers, no LDS staging
    for (long long base = start + (long long)tid * 4; base < end;
         base += (long long)BTHREADS * 4) {
        int   kk[4]; float vv[4]; int cnt;
        if (base + 4 <= end) {
            int4   k4 = *(const int4*)(idx + base);
            float4 v4 = *(const float4*)(vals + base);
            kk[0]=k4.x; kk[1]=k4.y; kk[2]=k4.z; kk[3]=k4.w;
            vv[0]=v4.x; vv[1]=v4.y; vv[2]=v4.z; vv[3]=v4.w;
            cnt = 4;
        } else {
            cnt = (int)(end - base);
            #pragma unroll
            for (int i = 0; i < 4; ++i) { kk[i] = 0; vv[i] = 0.0f; }
            for (int i = 0; i < cnt; ++i) { kk[i] = idx[base+i]; vv[i] = vals[base+i]; }
        }

        int bs[4]; unsigned recs[4]; int pos[4];
        #pragma unroll
        for (int j = 0; j < 4; ++j) {
            unsigned uk = (unsigned)kk[j];
            bs[j] = (int)(uk >> SLOT_BITS);
            float z = (vv[j] - t2) * inv_t1;
            float u = 0.5f * z * z;
            unsigned q = __float2uint_rn(fminf(u * QSCALE, (float)QMASK));
            recs[j] = ((uk & (SLOTS - 1)) << 18) | q;
        }
        #pragma unroll
        for (int j = 0; j < 4; ++j) {
            pos[j] = (j < cnt && bs[j] < nbuckets)
                     ? atomicAdd(&scnt[bs[j]], 1) : INT_MAX;
        }
        #pragma unroll
        for (int j = 0; j < 4; ++j) {
            if (pos[j] == INT_MAX) continue;
            if (pos[j] < cap)
                pairs[(region_idx(blk, bs[j], nbuckets, swzmask) << cap_shift)
                      + pos[j]] = recs[j];
            else
                ovf_push(ovf, ovf_cnt, ovcap, (unsigned)kk[j], recs[j] & QMASK);
        }
    }

    __syncthreads();
    for (int b = tid; b < nbuckets; b += BTHREADS) {
        int c = scnt[b]; if (c > cap) c = cap;
        fill[region_idx(blk, b, nbuckets, swzmask)] = c;
    }
}

__global__ __launch_bounds__(1024) void reduce_kernel(
        const unsigned* __restrict__ pairs, const int* __restrict__ fill,
        const uint2* __restrict__ ovf, const int* __restrict__ ovf_cnt, int ovcap,
        const float* __restrict__ thetas, float* __restrict__ out,
        long long n_out, int nbuckets, int cap_shift, int swzmask) {
    __shared__ unsigned accu[SLOTS];   // 64 KB packed: count<<25 | sum_q
    const int tid = threadIdx.x;
    const int b = blockIdx.x;

    for (int s = tid; s < SLOTS; s += 1024) accu[s] = 0u;
    __syncthreads();

    const int wave = tid >> 6, lane = tid & 63;
    const int SEGS = NBLK / 16;   // 32 segments per wave

    // preload this wave's segment counts: lane i holds cnt(seg wave+i*16)
    int sl = wave + (lane & 31) * 16;
    int cntv = fill[region_idx(sl, b, nbuckets, swzmask)];

    // pipelined segment stream: records read unconditionally (2x256B/seg)
    const unsigned* pc = pairs +
        (region_idx(wave, b, nbuckets, swzmask) << cap_shift);
    unsigned a0 = pc[lane];
    unsigned a1 = pc[64 + lane];

    for (int i = 0; i < SEGS; ++i) {
        const unsigned* pn = pc; unsigned n0 = 0, n1 = 0;
        if (i < SEGS - 1) {
            int sn = wave + (i + 1) * 16;
            pn = pairs + (region_idx(sn, b, nbuckets, swzmask) << cap_shift);
            n0 = pn[lane];
            n1 = pn[64 + lane];
        }
        int ca = __builtin_amdgcn_readlane(cntv, i);
        if (lane < ca)      atomicAdd(&accu[a0 >> 18], (1u << 25) + (a0 & QMASK));
        if (64 + lane < ca) atomicAdd(&accu[a1 >> 18], (1u << 25) + (a1 & QMASK));
        for (int r = 128 + lane; r < ca; r += 64) {   // only if cap > 128
            unsigned rec = pc[r];
            atomicAdd(&accu[rec >> 18], (1u << 25) + (rec & QMASK));
        }
        pc = pn; a0 = n0; a1 = n1;
    }
    __syncthreads();

    int no = *ovf_cnt; if (no > ovcap) no = ovcap;
    for (int i = tid; i < no; i += 1024) {
        uint2 e = ovf[i];
        if ((int)(e.x >> SLOT_BITS) == b)
            atomicAdd(&accu[e.x & (SLOTS - 1)], (1u << 25) + e.y);
    }
    __syncthreads();

    const float t1 = thetas[1];
    const float t0c = fminf(fmaxf(thetas[0], 0.0f), 1.0f);
    const float logC = logf(t0c * INV_SQRT_2PI / t1);
    const float cond = 1.0f - t0c;
    long long obase = (long long)b << SLOT_BITS;
    for (int ss = tid; ss < SLOTS; ss += 1024) {
        long long o = obase + ss;
        if (o < n_out) {
            unsigned av = accu[ss];
            float v = (float)(av >> 25) * logC
                    - (float)(av & 0x1FFFFFFu) * (1.0f / QSCALE);
            out[o] = cond * expf(v);
        }
    }
}

// ---- fallback path: direct global atomics (R1) ----
__global__ void init_zero_kernel(float* __restrict__ out, int n) {
    int i = blockIdx.x * blockDim.x + threadIdx.x;
    int stride = gridDim.x * blockDim.x;
    for (; i < n; i += stride) out[i] = 0.0f;
}
__global__ void scatter_log_kernel(const int* __restrict__ idx,
                                   const float* __restrict__ vals,
                                   const float* __restrict__ thetas,
                                   float* __restrict__ acc, int n) {
    float t1 = thetas[1], t2 = thetas[2];
    float t0c = fminf(fmaxf(thetas[0], 0.0f), 1.0f);
    float logC = logf(t0c * INV_SQRT_2PI / t1);
    float inv_t1 = 1.0f / t1;
    int i = blockIdx.x * blockDim.x + threadIdx.x;
    int stride = gridDim.x * blockDim.x;
    for (; i < n; i += stride) {
        float z = (vals[i] - t2) * inv_t1;
        atomicAdd(&acc[idx[i]], fmaf(-0.5f * z, z, logC));
    }
}
__global__ void finalize_kernel(float* __restrict__ out,
                                const float* __restrict__ thetas, int n) {
    float t0c = fminf(fmaxf(thetas[0], 0.0f), 1.0f);
    float cond = 1.0f - t0c;
    int i = blockIdx.x * blockDim.x + threadIdx.x;
    int stride = gridDim.x * blockDim.x;
    for (; i < n; i += stride) out[i] = cond * expf(out[i]);
}

extern "C" void kernel_launch(void* const* d_in, const int* in_sizes, int n_in,
                              void* d_out, int out_size, void* d_ws, size_t ws_size,
                              hipStream_t stream) {
    // inputs: [0]=batch (scalar), [1]=idx (int32), [2]=vals (f32), [3]=thetas (f32 x3)
    const int*   idx    = (const int*)d_in[1];
    const float* vals   = (const float*)d_in[2];
    const float* thetas = (const float*)d_in[3];
    float*       out    = (float*)d_out;

    int n_events = in_sizes[1];
    long long n_out = out_size;
    int nbuckets = (int)((n_out + SLOTS - 1) >> SLOT_BITS);

    // geometry
    long long epb_ll = (((long long)n_events + NBLK - 1) / NBLK + 2047) & ~2047LL;
    int epb = (int)epb_ll;
    long long avg = nbuckets > 0 ? (epb + nbuckets - 1) / nbuckets : 1;
    long long want = avg + avg / 2 + 32;        // Poisson mean avg, >>6 sigma
    int cap_shift = 6;
    while ((1LL << cap_shift) < want && cap_shift < 20) ++cap_shift;
    long long cappb = 1LL << cap_shift;
    int swzmask = (nbuckets > 0 && (nbuckets & (nbuckets - 1)) == 0)
                  ? nbuckets - 1 : 0;

    size_t pairs_b = (size_t)NBLK * nbuckets * cappb * 4;
    size_t fill_b  = (size_t)NBLK * nbuckets * 4;
    size_t head    = pairs_b + fill_b + 64;
    bool fast = (nbuckets > 0) && (nbuckets <= NB_MAX) && (n_events > 0) &&
                (ws_size >= head + 64 * 1024);

    if (fast) {
        unsigned* pairs = (unsigned*)d_ws;
        int* fill = (int*)((char*)d_ws + pairs_b);
        int* ovf_cnt = (int*)((char*)d_ws + pairs_b + fill_b);
        uint2* ovf = (uint2*)((char*)d_ws + head);
        long long ovcap_ll = (long long)((ws_size - head) / 8);
        int ovcap = (int)(ovcap_ll > 4194304 ? 4194304 : ovcap_ll);

        hipMemsetAsync(ovf_cnt, 0, sizeof(int), stream);
        bin_kernel<<<NBLK, BTHREADS, 0, stream>>>(idx, vals, thetas, pairs, fill,
                                                  ovf, ovf_cnt, ovcap,
                                                  n_events, nbuckets, cap_shift,
                                                  swzmask, epb);
        reduce_kernel<<<nbuckets, 1024, 0, stream>>>(pairs, fill, ovf, ovf_cnt,
                                                     ovcap, thetas, out,
                                                     n_out, nbuckets, cap_shift,
                                                     swzmask);
    } else {
        const int BLOCK = 256;
        int grid_out = min((int)((n_out + BLOCK - 1) / BLOCK), 2048);
        int grid_ev  = min((n_events + BLOCK - 1) / BLOCK, 2048);
        init_zero_kernel<<<grid_out, BLOCK, 0, stream>>>(out, (int)n_out);
        scatter_log_kernel<<<grid_ev, BLOCK, 0, stream>>>(idx, vals, thetas, out, n_events);
        finalize_kernel<<<grid_out, BLOCK, 0, stream>>>(out, thetas, (int)n_out);
    }
}

// Round 15
// 96.686 us; speedup vs baseline: 2.8795x; 2.8795x over previous
//
#include <hip/hip_runtime.h>
#include <climits>

// out[i] = cond * prod_{e: idx[e]==i} factor[e];  cond = 1 - clip(t0,0,1)
// log(factor) = logC - u,  u = 0.5*((v-t2)/t1)^2,  logC = log(t0c*INV_SQRT_2PI/t1)
//
// R15 = R11 (best measured: 96.4 us). Bin: 1024 threads (32 waves/CU),
// ONE rtn atomic per event returns position AND flush window (packed
// (J<<20)|count), slot-major ring [32][nb] (flush reads bank-b%32 scalar
// b32, 2-way aliasing = free), LDS-only barriers. Reduce: 1024 threads,
// packed int LDS atomics (count<<25 | sum_q), readlane counts, region
// swizzle, 2-deep segment pipeline.
//
// Elimination record (R1-R14): direct global f32 atomics 806us (20.7G/s
// memory-side RMW wall); direct 4B global scatter 220us (4x write amp,
// L2 can't hold the window); LDS-staged variants all 77-86us regardless
// of barrier structure / occupancy / flush scheme -> bound by the
// per-event ds_add_rtn + scattered ds_write pair.

#define INV_SQRT_2PI 0.39894246f  // 1/sqrt(2*3.14159) (matches reference)
#define SLOT_BITS 14
#define SLOTS (1 << SLOT_BITS)
#define NB_MAX 512          // max buckets for fast path
#define NBLK 512            // binning blocks (block-private regions)
#define BTHREADS 1024       // bin block threads
#define TILE 4096           // events per block-tile (4 per thread)
#define RING 32             // ring slots per bucket (pow2, two 16-rec halves)
#define QSCALE 8192.0f
#define QMASK 0x3FFFFu      // 18 bits
#define CMASK 0xFFFFFu      // low 20 bits of scnt = record count

#define LDS_BAR() do {                                        \
    asm volatile("s_waitcnt lgkmcnt(0)" ::: "memory");        \
    __builtin_amdgcn_s_barrier();                             \
} while (0)

__device__ __forceinline__ long long region_idx(int blk, int b, int nbuckets,
                                                int swzmask) {
    int bb = swzmask ? ((b + blk) & swzmask) : b;
    return (long long)blk * nbuckets + bb;
}

__device__ __forceinline__ void ovf_push(uint2* ovf, int* ovf_cnt, int ovcap,
                                         unsigned gslot, unsigned q) {
    int op = atomicAdd(ovf_cnt, 1);
    if (op < ovcap) ovf[op] = make_uint2(gslot, q);
}

__global__ __launch_bounds__(BTHREADS) void bin_kernel(
        const int* __restrict__ idx, const float* __restrict__ vals,
        const float* __restrict__ thetas,
        unsigned* __restrict__ pairs,  // [NBLK][nbuckets][cappb] (swizzled)
        int* __restrict__ fill,        // [NBLK][nbuckets] valid counts (swizzled)
        uint2* __restrict__ ovf, int* __restrict__ ovf_cnt, int ovcap,
        int n, int nbuckets, int cap_shift, int swzmask, int epb) {
    __shared__ unsigned ring[RING * NB_MAX];   // slot-major [32][nb], 64 KB
    __shared__ int scnt[NB_MAX];               // packed (chunks<<20)|count

    const int tid = threadIdx.x;
    const int blk = blockIdx.x;
    const int cappb = 1 << cap_shift;
    long long start = (long long)blk * epb;
    long long end = start + epb;
    if (end > n) end = n;

    for (int b = tid; b < nbuckets; b += BTHREADS) scnt[b] = 0;
    __syncthreads();

    const float t1 = thetas[1], t2 = thetas[2];
    const float t0c = fminf(fmaxf(thetas[0], 0.0f), 1.0f);
    const float inv_t1 = 1.0f / t1;

    // prefetch tile 0 (4 events/thread: one int4 + one float4)
    int4 ck = make_int4(0,0,0,0); float4 cv = make_float4(0,0,0,0); int ccnt = 0;
    int4 pk_; float4 pv_;
    {
        long long te0 = start + TILE; if (te0 > end) te0 = end;
        long long base = start + (long long)tid * 4;
        if (base + 4 <= te0) {
            ck = *(const int4*)(idx + base);
            cv = *(const float4*)(vals + base);
            ccnt = 4;
        } else if (base < te0) {
            ccnt = (int)(te0 - base);
            int kk[4] = {0,0,0,0}; float vv[4] = {0,0,0,0};
            for (int i = 0; i < ccnt; ++i) { kk[i]=idx[base+i]; vv[i]=vals[base+i]; }
            ck = make_int4(kk[0],kk[1],kk[2],kk[3]);
            cv = make_float4(vv[0],vv[1],vv[2],vv[3]);
        }
    }

    for (long long ts = start; ts < end; ts += TILE) {
        // ---- prefetch next tile ----
        int ncnt = 0;
        long long tsn = ts + TILE;
        if (tsn < end) {
            long long ten = tsn + TILE; if (ten > end) ten = end;
            long long base = tsn + (long long)tid * 4;
            if (base + 4 <= ten) {
                pk_ = *(const int4*)(idx + base);
                pv_ = *(const float4*)(vals + base);
                ncnt = 4;
            } else if (base < ten) {
                ncnt = (int)(ten - base);
                int kk[4] = {0,0,0,0}; float vv[4] = {0,0,0,0};
                for (int i = 0; i < ncnt; ++i) { kk[i]=idx[base+i]; vv[i]=vals[base+i]; }
                pk_ = make_int4(kk[0],kk[1],kk[2],kk[3]);
                pv_ = make_float4(vv[0],vv[1],vv[2],vv[3]);
            }
        }

        // ---- compute records ----
        int   kk[4] = {ck.x, ck.y, ck.z, ck.w};
        float vv[4] = {cv.x, cv.y, cv.z, cv.w};
        int bs[4]; unsigned recs[4];
        #pragma unroll
        for (int j = 0; j < 4; ++j) {
            unsigned uk = (unsigned)kk[j];
            bs[j] = (int)(uk >> SLOT_BITS);
            float z = (vv[j] - t2) * inv_t1;
            float u = 0.5f * z * z;
            unsigned q = __float2uint_rn(fminf(u * QSCALE, (float)QMASK));
            recs[j] = ((uk & (SLOTS - 1)) << 18) | q;
        }
        // ---- one atomic per event returns pos AND flush window ----
        int ret[4];
        #pragma unroll
        for (int j = 0; j < 4; ++j) {
            ret[j] = (j < ccnt && bs[j] < nbuckets)
                     ? atomicAdd(&scnt[bs[j]], 1) : INT_MIN;
        }
        #pragma unroll
        for (int j = 0; j < 4; ++j) {
            if (ret[j] == INT_MIN) continue;
            int pos = ret[j] & CMASK;
            int fl  = (ret[j] >> 20) << 4;     // chunks flushed * 16
            if (pos - fl < RING)
                ring[(pos & (RING - 1)) * nbuckets + bs[j]] = recs[j];
            else
                ovf_push(ovf, ovf_cnt, ovcap, (unsigned)kk[j], recs[j] & QMASK);
        }
        LDS_BAR();

        // ---- flush whole 16-record halves (conflict-free b%32 reads) ----
        for (int b = tid; b < nbuckets; b += BTHREADS) {
            int pk = scnt[b];
            int c = pk & CMASK;
            int J = pk >> 20;
            int fl = J << 4;
            int se = c < fl + RING ? c : fl + RING;   // clamp spilled tail
            int na = se - fl;
            int J0 = J;
            while (na >= 16) {
                int H = (J & 1) << 4;                 // physical half base slot
                unsigned tmp[16];
                #pragma unroll
                for (int i = 0; i < 16; ++i)
                    tmp[i] = ring[(H + i) * nbuckets + b];
                if (J < (cappb >> 4)) {
                    uint4* d4 = (uint4*)(pairs +
                        (region_idx(blk, b, nbuckets, swzmask) << cap_shift) + (J << 4));
                    const uint4* t4 = (const uint4*)tmp;
                    d4[0]=t4[0]; d4[1]=t4[1]; d4[2]=t4[2]; d4[3]=t4[3];
                } else {  // region full (practically never)
                    for (int i = 0; i < 16; ++i) {
                        unsigned r = tmp[i];
                        ovf_push(ovf, ovf_cnt, ovcap,
                                 ((unsigned)b << SLOT_BITS) | (r >> 18), r & QMASK);
                    }
                }
                ++J; fl += 16; na -= 16;
            }
            if (J != J0 || se != c) scnt[b] = (J << 20) | se;
        }
        LDS_BAR();

        ck = pk_; cv = pv_; ccnt = ncnt;
    }

    // ---- final flush: partial chunk (logical order = slot order) ----
    for (int b = tid; b < nbuckets; b += BTHREADS) {
        int pk = scnt[b];
        int c = pk & CMASK;
        int J = pk >> 20;
        int fl = J << 4;
        int r = c - fl;                      // 0..15 (window-clamped in loop)
        int valid = fl;
        if (r > 0 && J < (cappb >> 4)) {
            int H = (J & 1) << 4;
            unsigned tmp[16];
            #pragma unroll
            for (int i = 0; i < 16; ++i)
                tmp[i] = ring[(H + i) * nbuckets + b];
            uint4* d4 = (uint4*)(pairs +
                (region_idx(blk, b, nbuckets, swzmask) << cap_shift) + (J << 4));
            const uint4* t4 = (const uint4*)tmp;
            d4[0]=t4[0]; d4[1]=t4[1]; d4[2]=t4[2]; d4[3]=t4[3];
            valid = fl + r;
        } else if (r > 0) {
            int H = (J & 1) << 4;
            for (int i = 0; i < r; ++i) {
                unsigned rr = ring[(H + i) * nbuckets + b];
                ovf_push(ovf, ovf_cnt, ovcap,
                         ((unsigned)b << SLOT_BITS) | (rr >> 18), rr & QMASK);
            }
        }
        fill[region_idx(blk, b, nbuckets, swzmask)] = valid;
    }
}

__global__ __launch_bounds__(1024) void reduce_kernel(
        const unsigned* __restrict__ pairs, const int* __restrict__ fill,
        const uint2* __restrict__ ovf, const int* __restrict__ ovf_cnt, int ovcap,
        const float* __restrict__ thetas, float* __restrict__ out,
        long long n_out, int nbuckets, int cap_shift, int swzmask) {
    __shared__ unsigned accu[SLOTS];   // 64 KB packed: count<<25 | sum_q
    const int tid = threadIdx.x;
    const int b = blockIdx.x;

    for (int s = tid; s < SLOTS; s += 1024) accu[s] = 0u;
    __syncthreads();

    const int wave = tid >> 6, lane = tid & 63;
    const int SEGS = NBLK / 16;   // 32 segments per wave

    // preload this wave's segment counts: lane i holds cnt(seg wave+i*16)
    int sl = wave + (lane & 31) * 16;
    int cntv = fill[region_idx(sl, b, nbuckets, swzmask)];

    // pipelined segment stream: records read unconditionally (2x256B/seg)
    const unsigned* pc = pairs +
        (region_idx(wave, b, nbuckets, swzmask) << cap_shift);
    unsigned a0 = pc[lane];
    unsigned a1 = pc[64 + lane];

    for (int i = 0; i < SEGS; ++i) {
        const unsigned* pn = pc; unsigned n0 = 0, n1 = 0;
        if (i < SEGS - 1) {
            int sn = wave + (i + 1) * 16;
            pn = pairs + (region_idx(sn, b, nbuckets, swzmask) << cap_shift);
            n0 = pn[lane];
            n1 = pn[64 + lane];
        }
        int ca = __builtin_amdgcn_readlane(cntv, i);
        if (lane < ca)      atomicAdd(&accu[a0 >> 18], (1u << 25) + (a0 & QMASK));
        if (64 + lane < ca) atomicAdd(&accu[a1 >> 18], (1u << 25) + (a1 & QMASK));
        for (int r = 128 + lane; r < ca; r += 64) {   // only if cap_shift > 7
            unsigned rec = pc[r];
            atomicAdd(&accu[rec >> 18], (1u << 25) + (rec & QMASK));
        }
        pc = pn; a0 = n0; a1 = n1;
    }
    __syncthreads();

    int no = *ovf_cnt; if (no > ovcap) no = ovcap;
    for (int i = tid; i < no; i += 1024) {
        uint2 e = ovf[i];
        if ((int)(e.x >> SLOT_BITS) == b)
            atomicAdd(&accu[e.x & (SLOTS - 1)], (1u << 25) + e.y);
    }
    __syncthreads();

    const float t1 = thetas[1];
    const float t0c = fminf(fmaxf(thetas[0], 0.0f), 1.0f);
    const float logC = logf(t0c * INV_SQRT_2PI / t1);
    const float cond = 1.0f - t0c;
    long long obase = (long long)b << SLOT_BITS;
    for (int ss = tid; ss < SLOTS; ss += 1024) {
        long long o = obase + ss;
        if (o < n_out) {
            unsigned av = accu[ss];
            float v = (float)(av >> 25) * logC
                    - (float)(av & 0x1FFFFFFu) * (1.0f / QSCALE);
            out[o] = cond * expf(v);
        }
    }
}

// ---- fallback path: direct global atomics (R1) ----
__global__ void init_zero_kernel(float* __restrict__ out, int n) {
    int i = blockIdx.x * blockDim.x + threadIdx.x;
    int stride = gridDim.x * blockDim.x;
    for (; i < n; i += stride) out[i] = 0.0f;
}
__global__ void scatter_log_kernel(const int* __restrict__ idx,
                                   const float* __restrict__ vals,
                                   const float* __restrict__ thetas,
                                   float* __restrict__ acc, int n) {
    float t1 = thetas[1], t2 = thetas[2];
    float t0c = fminf(fmaxf(thetas[0], 0.0f), 1.0f);
    float logC = logf(t0c * INV_SQRT_2PI / t1);
    float inv_t1 = 1.0f / t1;
    int i = blockIdx.x * blockDim.x + threadIdx.x;
    int stride = gridDim.x * blockDim.x;
    for (; i < n; i += stride) {
        float z = (vals[i] - t2) * inv_t1;
        atomicAdd(&acc[idx[i]], fmaf(-0.5f * z, z, logC));
    }
}
__global__ void finalize_kernel(float* __restrict__ out,
                                const float* __restrict__ thetas, int n) {
    float t0c = fminf(fmaxf(thetas[0], 0.0f), 1.0f);
    float cond = 1.0f - t0c;
    int i = blockIdx.x * blockDim.x + threadIdx.x;
    int stride = gridDim.x * blockDim.x;
    for (; i < n; i += stride) out[i] = cond * expf(out[i]);
}

extern "C" void kernel_launch(void* const* d_in, const int* in_sizes, int n_in,
                              void* d_out, int out_size, void* d_ws, size_t ws_size,
                              hipStream_t stream) {
    // inputs: [0]=batch (scalar), [1]=idx (int32), [2]=vals (f32), [3]=thetas (f32 x3)
    const int*   idx    = (const int*)d_in[1];
    const float* vals   = (const float*)d_in[2];
    const float* thetas = (const float*)d_in[3];
    float*       out    = (float*)d_out;

    int n_events = in_sizes[1];
    long long n_out = out_size;
    int nbuckets = (int)((n_out + SLOTS - 1) >> SLOT_BITS);

    // geometry
    long long tiles_total = ((long long)n_events + TILE - 1) / TILE;
    long long tpb = (tiles_total + NBLK - 1) / NBLK;
    int epb = (int)(tpb * TILE);
    long long avg = nbuckets > 0 ? (epb + nbuckets - 1) / nbuckets : 1;
    long long want = avg + avg / 2 + 32;        // Poisson mean avg, >>6 sigma
    int cap_shift = 6;
    while ((1LL << cap_shift) < want && cap_shift < 20) ++cap_shift;
    long long cappb = 1LL << cap_shift;
    int swzmask = (nbuckets > 0 && (nbuckets & (nbuckets - 1)) == 0)
                  ? nbuckets - 1 : 0;

    size_t pairs_b = (size_t)NBLK * nbuckets * cappb * 4;
    size_t fill_b  = (size_t)NBLK * nbuckets * 4;
    size_t head    = pairs_b + fill_b + 64;
    bool fast = (nbuckets > 0) && (nbuckets <= NB_MAX) && (n_events > 0) &&
                (ws_size >= head + 64 * 1024);

    if (fast) {
        unsigned* pairs = (unsigned*)d_ws;
        int* fill = (int*)((char*)d_ws + pairs_b);
        int* ovf_cnt = (int*)((char*)d_ws + pairs_b + fill_b);
        uint2* ovf = (uint2*)((char*)d_ws + head);
        long long ovcap_ll = (long long)((ws_size - head) / 8);
        int ovcap = (int)(ovcap_ll > 4194304 ? 4194304 : ovcap_ll);

        hipMemsetAsync(ovf_cnt, 0, sizeof(int), stream);
        bin_kernel<<<NBLK, BTHREADS, 0, stream>>>(idx, vals, thetas, pairs, fill,
                                                  ovf, ovf_cnt, ovcap,
                                                  n_events, nbuckets, cap_shift,
                                                  swzmask, epb);
        reduce_kernel<<<nbuckets, 1024, 0, stream>>>(pairs, fill, ovf, ovf_cnt,
                                                     ovcap, thetas, out,
                                                     n_out, nbuckets, cap_shift,
                                                     swzmask);
    } else {
        const int BLOCK = 256;
        int grid_out = min((int)((n_out + BLOCK - 1) / BLOCK), 2048);
        int grid_ev  = min((n_events + BLOCK - 1) / BLOCK, 2048);
        init_zero_kernel<<<grid_out, BLOCK, 0, stream>>>(out, (int)n_out);
        scatter_log_kernel<<<grid_ev, BLOCK, 0, stream>>>(idx, vals, thetas, out, n_events);
        finalize_kernel<<<grid_out, BLOCK, 0, stream>>>(out, thetas, (int)n_out);
    }
}